// Round 1
// baseline (111.346 us; speedup 1.0000x reference)
//
#include <hip/hip_runtime.h>

// out[b,o] = max_k min(x[b,k], w[k,o])   (forward of the straight-through
// smooth-max — stop_gradient(hard - smooth) + smooth == hard numerically)
//
// M=1024 (batch), K=512 (in), N=512 (out), all fp32.
//
// Design: wave tile = MB(8) m-rows x 64 n-lanes. x[m][k] is wave-uniform
// (lanes differ only in n) -> scalar s_load path; w[k][n] is a coalesced
// 256B/wave load, L1/L2 resident (w-tile per block = 256 cols x K rows).
// No LDS, no barriers. max(max(a,b),c) should combine to v_max3_f32.

#define MB 8
#define NB 256
#define KDIM 512
#define NDIM 512

__global__ __launch_bounds__(256) void SmoothSTEMaxMin_kernel(
    const float* __restrict__ x,
    const float* __restrict__ w,
    float* __restrict__ out)
{
    const int n  = blockIdx.y * NB + threadIdx.x;   // out column (lane-contig)
    const int m0 = blockIdx.x * MB;                 // first batch row of block
    const float* __restrict__ xrow = x + (size_t)m0 * KDIM;

    float acc[MB];
#pragma unroll
    for (int r = 0; r < MB; ++r) acc[r] = -3.0e38f;

    for (int k = 0; k < KDIM; k += 8) {
        // 8 rows of w for this lane's column (per-lane, coalesced across wave)
        float wv[8];
#pragma unroll
        for (int u = 0; u < 8; ++u) wv[u] = w[(size_t)(k + u) * NDIM + n];

#pragma unroll
        for (int r = 0; r < MB; ++r) {
            // x reads are wave-uniform -> expect s_load + SGPR broadcast
            const float* __restrict__ xr = xrow + (size_t)r * KDIM + k;
#pragma unroll
            for (int u = 0; u < 8; u += 2) {
                float a0 = fminf(xr[u],     wv[u]);
                float a1 = fminf(xr[u + 1], wv[u + 1]);
                acc[r] = fmaxf(acc[r], fmaxf(a0, a1));   // -> v_max3_f32
            }
        }
    }

#pragma unroll
    for (int r = 0; r < MB; ++r)
        out[(size_t)(m0 + r) * NDIM + n] = acc[r];
}

extern "C" void kernel_launch(void* const* d_in, const int* in_sizes, int n_in,
                              void* d_out, int out_size, void* d_ws, size_t ws_size,
                              hipStream_t stream) {
    const float* x = (const float*)d_in[0];   // (1024, 512)
    const float* w = (const float*)d_in[1];   // (512, 512)
    float* out = (float*)d_out;               // (1024, 512)

    dim3 grid(1024 / MB, NDIM / NB);          // 128 x 2 = 256 blocks
    dim3 block(NB);                           // 256 threads = 4 waves
    SmoothSTEMaxMin_kernel<<<grid, block, 0, stream>>>(x, w, out);
}

// Round 2
// 102.290 us; speedup vs baseline: 1.0885x; 1.0885x over previous
//
#include <hip/hip_runtime.h>
#include <float.h>

// out[m,n] = max_k min(x[m,k], w[k,n])  — tropical matmul, M=1024 K=512 N=512 fp32.
//
// 3-kernel pipeline:
//  1) transpose_w:  wT[n][k] = w[k][n]  (1 MB in ws) -> per-lane contiguous k-streams
//  2) tropical_main: k-split x2 for occupancy (2048 waves = 2/SIMD).
//     Wave tile: 8 m-rows x 64 n-lanes, half of K. x reads are wave-uniform
//     (SGPR/s_load path); w reads are per-lane contiguous dwordx4 with explicit
//     2-stage prefetch. Inner op: 4 fmin + 2 v_max3 per 4k per row.
//  3) combine_max: out = max(partial_k0, partial_k1)
//
// ws layout: [0,1MB) wT ; [1MB,5MB) partials (2 x 1024x512 f32)

#define MDIM 1024
#define KDIM 512
#define NDIM 512

__global__ __launch_bounds__(256) void transpose_w(const float* __restrict__ w,
                                                   float* __restrict__ wT) {
    const int n = blockIdx.x;            // 0..511
    const int k = threadIdx.x;           // 0..255
    // writes coalesced over k; strided reads are L2-absorbed (w is 1 MB)
    wT[(size_t)n * KDIM + k]       = w[(size_t)k * NDIM + n];
    wT[(size_t)n * KDIM + k + 256] = w[(size_t)(k + 256) * NDIM + n];
}

__global__ __launch_bounds__(256) void tropical_main(const float* __restrict__ x,
                                                     const float* __restrict__ wT,
                                                     float* __restrict__ part) {
    const int n  = blockIdx.y * 256 + threadIdx.x;   // out column
    const int m0 = blockIdx.x * 8;                   // 8 batch rows per block
    const int kh = blockIdx.z;                       // k-half: 0 or 1
    const float4* __restrict__ wrow = (const float4*)(wT + (size_t)n * KDIM + kh * 256);
    const float*  __restrict__ xb   = x + (size_t)m0 * KDIM + kh * 256;

    float acc[8];
#pragma unroll
    for (int r = 0; r < 8; ++r) acc[r] = -FLT_MAX;

    // explicit 2-stage pipeline over 16 chunks of 16 k's (4 float4 each)
    float4 cur0 = wrow[0], cur1 = wrow[1], cur2 = wrow[2], cur3 = wrow[3];

    for (int c = 0; c < 64; c += 4) {
        float4 nxt0, nxt1, nxt2, nxt3;
        if (c + 4 < 64) {
            nxt0 = wrow[c + 4]; nxt1 = wrow[c + 5];
            nxt2 = wrow[c + 6]; nxt3 = wrow[c + 7];
        }
        const float* xc = xb + c * 4;
#pragma unroll
        for (int r = 0; r < 8; ++r) {
            const float* __restrict__ xr = xc + r * KDIM;  // wave-uniform -> s_load
            float a = acc[r];
            {
                float t0 = fminf(xr[0],  cur0.x);
                float t1 = fminf(xr[1],  cur0.y);
                float t2 = fminf(xr[2],  cur0.z);
                float t3 = fminf(xr[3],  cur0.w);
                a = fmaxf(fmaxf(a, t0), t1);    // v_max3
                a = fmaxf(fmaxf(a, t2), t3);    // v_max3
            }
            {
                float t0 = fminf(xr[4],  cur1.x);
                float t1 = fminf(xr[5],  cur1.y);
                float t2 = fminf(xr[6],  cur1.z);
                float t3 = fminf(xr[7],  cur1.w);
                a = fmaxf(fmaxf(a, t0), t1);
                a = fmaxf(fmaxf(a, t2), t3);
            }
            {
                float t0 = fminf(xr[8],  cur2.x);
                float t1 = fminf(xr[9],  cur2.y);
                float t2 = fminf(xr[10], cur2.z);
                float t3 = fminf(xr[11], cur2.w);
                a = fmaxf(fmaxf(a, t0), t1);
                a = fmaxf(fmaxf(a, t2), t3);
            }
            {
                float t0 = fminf(xr[12], cur3.x);
                float t1 = fminf(xr[13], cur3.y);
                float t2 = fminf(xr[14], cur3.z);
                float t3 = fminf(xr[15], cur3.w);
                a = fmaxf(fmaxf(a, t0), t1);
                a = fmaxf(fmaxf(a, t2), t3);
            }
            acc[r] = a;
        }
        cur0 = nxt0; cur1 = nxt1; cur2 = nxt2; cur3 = nxt3;
    }

    float* p = part + (size_t)kh * (MDIM * NDIM) + (size_t)m0 * NDIM + n;
#pragma unroll
    for (int r = 0; r < 8; ++r) p[(size_t)r * NDIM] = acc[r];
}

__global__ __launch_bounds__(256) void combine_max(const float* __restrict__ part,
                                                   float* __restrict__ out) {
    const size_t i = (size_t)blockIdx.x * 256 + threadIdx.x;  // 131072 float4s
    const float4* __restrict__ p0 = (const float4*)part;
    const float4* __restrict__ p1 = (const float4*)(part + (size_t)MDIM * NDIM);
    float4 a = p0[i], b = p1[i];
    float4 o;
    o.x = fmaxf(a.x, b.x); o.y = fmaxf(a.y, b.y);
    o.z = fmaxf(a.z, b.z); o.w = fmaxf(a.w, b.w);
    ((float4*)out)[i] = o;
}

extern "C" void kernel_launch(void* const* d_in, const int* in_sizes, int n_in,
                              void* d_out, int out_size, void* d_ws, size_t ws_size,
                              hipStream_t stream) {
    const float* x = (const float*)d_in[0];   // (1024, 512)
    const float* w = (const float*)d_in[1];   // (512, 512)
    float* out = (float*)d_out;               // (1024, 512)

    float* wT   = (float*)d_ws;                       // 512*512 floats = 1 MB
    float* part = (float*)d_ws + (size_t)KDIM * NDIM; // 2*1024*512 floats = 4 MB

    transpose_w<<<dim3(NDIM), dim3(256), 0, stream>>>(w, wT);
    tropical_main<<<dim3(MDIM / 8, NDIM / 256, 2), dim3(256), 0, stream>>>(x, wT, part);
    combine_max<<<dim3((MDIM * NDIM / 4) / 256), dim3(256), 0, stream>>>(part, out);
}

// Round 3
// 95.723 us; speedup vs baseline: 1.1632x; 1.0686x over previous
//
#include <hip/hip_runtime.h>
#include <float.h>

// out[m,n] = max_k min(x[m,k], w[k,n])  — tropical matmul, M=1024 K=512 N=512 fp32.
//
// Single fused kernel. Block = 256 threads = 4 waves, output tile 8 m x 64 n.
// K is split ACROSS THE 4 WAVES (128 k each) -> 1024 blocks (4/CU, 16 waves/CU)
// without any global partials; waves combine via an 8 KB LDS max-reduce.
// w is read in its native [k][n] layout: lane=n -> one coalesced 256B
// global_load_dword per k, double-buffered in registers (no v_mov shuffle).
// x[m][k] addresses are wave-uniform -> scalar s_load path.
// fmaxf(fmaxf(a,t0),t1) folds to v_max3_f32: 1.5 VALU ops per position,
// floor = 268M*1.5/32768 lanes/cy = 12.3K cy = 5.1 us.

#define MDIM 1024
#define KDIM 512
#define NDIM 512
#define MB 8     // m-rows per block
#define KW 128   // k per wave (4 waves cover K=512)

__global__ __launch_bounds__(256) void tropical_fused(
    const float* __restrict__ x,
    const float* __restrict__ w,
    float* __restrict__ out)
{
    const int lane = threadIdx.x & 63;
    const int wv   = threadIdx.x >> 6;              // 0..3
    const int n0   = blockIdx.y * 64;
    const int m0   = blockIdx.x * MB;
    const int k0   = wv * KW;

    const float* __restrict__ wp = w + (size_t)k0 * NDIM + n0 + lane;  // +=NDIM per k
    const float* __restrict__ xp = x + (size_t)m0 * KDIM + k0;         // wave-uniform

    float acc[MB];
#pragma unroll
    for (int r = 0; r < MB; ++r) acc[r] = -FLT_MAX;

    float wa[8], wb[8];

    auto load8 = [&](float* dst, int kb) {
#pragma unroll
        for (int u = 0; u < 8; ++u) dst[u] = wp[(size_t)(kb + u) * NDIM];
    };
    auto comp8 = [&](const float* wr, int kb) {
#pragma unroll
        for (int r = 0; r < MB; ++r) {
            const float* __restrict__ xr = xp + (size_t)r * KDIM + kb;  // uniform
            float a = acc[r];
            float t0 = fminf(xr[0], wr[0]);
            float t1 = fminf(xr[1], wr[1]);
            a = fmaxf(fmaxf(a, t0), t1);          // v_max3_f32
            float t2 = fminf(xr[2], wr[2]);
            float t3 = fminf(xr[3], wr[3]);
            a = fmaxf(fmaxf(a, t2), t3);
            float t4 = fminf(xr[4], wr[4]);
            float t5 = fminf(xr[5], wr[5]);
            a = fmaxf(fmaxf(a, t4), t5);
            float t6 = fminf(xr[6], wr[6]);
            float t7 = fminf(xr[7], wr[7]);
            a = fmaxf(fmaxf(a, t6), t7);
            acc[r] = a;
        }
    };

    load8(wa, 0);
    for (int kc = 0; kc < KW - 16; kc += 16) {    // kc = 0,16,...,96
        load8(wb, kc + 8);
        comp8(wa, kc);
        load8(wa, kc + 16);
        comp8(wb, kc + 8);
    }
    load8(wb, KW - 8);
    comp8(wa, KW - 16);
    comp8(wb, KW - 8);

    // intra-block k-reduction: 4 wave-partials -> 1, via LDS (8 KB)
    __shared__ float red[4][MB][64];
#pragma unroll
    for (int r = 0; r < MB; ++r) red[wv][r][lane] = acc[r];
    __syncthreads();

#pragma unroll
    for (int o = 0; o < 2; ++o) {                 // 512 outputs, 256 threads
        const int idx = threadIdx.x + o * 256;
        const int r = idx >> 6, l = idx & 63;
        float v = fmaxf(fmaxf(red[0][r][l], red[1][r][l]),
                        fmaxf(red[2][r][l], red[3][r][l]));
        out[(size_t)(m0 + r) * NDIM + n0 + l] = v;
    }
}

extern "C" void kernel_launch(void* const* d_in, const int* in_sizes, int n_in,
                              void* d_out, int out_size, void* d_ws, size_t ws_size,
                              hipStream_t stream) {
    const float* x = (const float*)d_in[0];   // (1024, 512)
    const float* w = (const float*)d_in[1];   // (512, 512)
    float* out = (float*)d_out;               // (1024, 512)

    dim3 grid(MDIM / MB, NDIM / 64);          // 128 x 8 = 1024 blocks
    tropical_fused<<<grid, dim3(256), 0, stream>>>(x, w, out);
}

// Round 4
// 79.177 us; speedup vs baseline: 1.4063x; 1.2090x over previous
//
#include <hip/hip_runtime.h>
#include <float.h>

// out[m,n] = max_k min(x[m,k], w[k,n])  — tropical matmul, M=1024 K=512 N=512 fp32.
//
// Single fused kernel. Block = 256 threads = 4 waves, output tile 8 m x 64 n.
// K split across the 4 waves (128 k each) -> 1024 blocks, LDS max-combine.
// w read in native [k][n] layout: lane=n -> coalesced 256B global_load_dword
// per k, register double-buffered. x[m][k] addresses are wave-uniform; k0 is
// routed through __builtin_amdgcn_readfirstlane so divergence analysis sees
// it as uniform -> x reads take the SMEM (s_load) path instead of per-lane
// vector loads (R3's 45us was exactly this: wv*KW marked divergent -> 1024
// broadcast global_loads/wave).

#define MDIM 1024
#define KDIM 512
#define NDIM 512
#define MB 8     // m-rows per block
#define KW 128   // k per wave (4 waves cover K=512)

__global__ __launch_bounds__(256) void tropical_fused(
    const float* __restrict__ x,
    const float* __restrict__ w,
    float* __restrict__ out)
{
    const int lane = threadIdx.x & 63;
    const int wv   = threadIdx.x >> 6;              // 0..3
    const int n0   = blockIdx.y * 64;
    const int m0   = blockIdx.x * MB;
    // wave-uniform k-offset, made PROVABLY uniform for the compiler:
    const int k0   = __builtin_amdgcn_readfirstlane(wv * KW);

    const float* __restrict__ wp = w + (size_t)(wv * KW) * NDIM + n0 + lane;
    const float* __restrict__ xp = x + (size_t)m0 * KDIM + k0;   // uniform -> s_load

    float acc[MB];
#pragma unroll
    for (int r = 0; r < MB; ++r) acc[r] = -FLT_MAX;

    float wa[8], wb[8];

    auto load8 = [&](float* dst, int kb) {
#pragma unroll
        for (int u = 0; u < 8; ++u) dst[u] = wp[(size_t)(kb + u) * NDIM];
    };
    auto comp8 = [&](const float* wr, int kb) {
#pragma unroll
        for (int r = 0; r < MB; ++r) {
            const float* __restrict__ xr = xp + (size_t)r * KDIM + kb;  // uniform
            float a = acc[r];
            float t0 = fminf(xr[0], wr[0]);
            float t1 = fminf(xr[1], wr[1]);
            a = fmaxf(fmaxf(a, t0), t1);          // v_max3_f32
            float t2 = fminf(xr[2], wr[2]);
            float t3 = fminf(xr[3], wr[3]);
            a = fmaxf(fmaxf(a, t2), t3);
            float t4 = fminf(xr[4], wr[4]);
            float t5 = fminf(xr[5], wr[5]);
            a = fmaxf(fmaxf(a, t4), t5);
            float t6 = fminf(xr[6], wr[6]);
            float t7 = fminf(xr[7], wr[7]);
            a = fmaxf(fmaxf(a, t6), t7);
            acc[r] = a;
        }
    };

    load8(wa, 0);
    for (int kc = 0; kc < KW - 16; kc += 16) {    // kc = 0,16,...,96
        load8(wb, kc + 8);
        comp8(wa, kc);
        load8(wa, kc + 16);
        comp8(wb, kc + 8);
    }
    load8(wb, KW - 8);
    comp8(wa, KW - 16);
    comp8(wb, KW - 8);

    // intra-block k-reduction: 4 wave-partials -> 1, via LDS (8 KB)
    __shared__ float red[4][MB][64];
#pragma unroll
    for (int r = 0; r < MB; ++r) red[wv][r][lane] = acc[r];
    __syncthreads();

#pragma unroll
    for (int o = 0; o < 2; ++o) {                 // 512 outputs, 256 threads
        const int idx = threadIdx.x + o * 256;
        const int r = idx >> 6, l = idx & 63;
        float v = fmaxf(fmaxf(red[0][r][l], red[1][r][l]),
                        fmaxf(red[2][r][l], red[3][r][l]));
        out[(size_t)(m0 + r) * NDIM + n0 + l] = v;
    }
}

extern "C" void kernel_launch(void* const* d_in, const int* in_sizes, int n_in,
                              void* d_out, int out_size, void* d_ws, size_t ws_size,
                              hipStream_t stream) {
    const float* x = (const float*)d_in[0];   // (1024, 512)
    const float* w = (const float*)d_in[1];   // (512, 512)
    float* out = (float*)d_out;               // (1024, 512)

    dim3 grid(MDIM / MB, NDIM / 64);          // 128 x 8 = 1024 blocks
    tropical_fused<<<grid, dim3(256), 0, stream>>>(x, w, out);
}